// Round 1
// baseline (493.176 us; speedup 1.0000x reference)
//
#include <hip/hip_runtime.h>

#define HIDDEN 128
#define SCAN_CHUNK 256
#define NCHUNK 8
#define CH 16  // floats per feature chunk (64 B)

typedef float vfloat4 __attribute__((ext_vector_type(4)));

// ---------------------------------------------------------------------------
// CSR build step 1: degree histogram over dst
// ---------------------------------------------------------------------------
__global__ __launch_bounds__(256) void hist_kernel(const int* __restrict__ dst,
                                                   int* __restrict__ deg, int E) {
  int e = blockIdx.x * blockDim.x + threadIdx.x;
  if (e < E) atomicAdd(&deg[dst[e]], 1);
}

// ---------------------------------------------------------------------------
// CSR scan phase A: per-block chunk sums (chunk = 256 elements, 1/thread)
// ---------------------------------------------------------------------------
__global__ __launch_bounds__(256) void scan_partial_kernel(
    const int* __restrict__ deg, int* __restrict__ partial, int N) {
  __shared__ int red[256];
  const int t = threadIdx.x;
  const int idx = blockIdx.x * SCAN_CHUNK + t;
  red[t] = (idx < N) ? deg[idx] : 0;
  __syncthreads();
#pragma unroll
  for (int off = 128; off; off >>= 1) {
    if (t < off) red[t] += red[t + off];
    __syncthreads();
  }
  if (t == 0) partial[blockIdx.x] = red[0];
}

// ---------------------------------------------------------------------------
// CSR scan phase B: one block scans the (<=256) block partials -> exclusive
// block offsets.
// ---------------------------------------------------------------------------
__global__ __launch_bounds__(256) void scan_offsets_kernel(
    const int* __restrict__ partial, int* __restrict__ blockOff, int nBlocks) {
  __shared__ int sums[256];
  const int t = threadIdx.x;
  const int p = (t < nBlocks) ? partial[t] : 0;
  sums[t] = p;
  __syncthreads();
#pragma unroll
  for (int off = 1; off < 256; off <<= 1) {
    int v = (t >= off) ? sums[t - off] : 0;
    __syncthreads();
    sums[t] += v;
    __syncthreads();
  }
  blockOff[t] = sums[t] - p;  // exclusive
}

// ---------------------------------------------------------------------------
// CSR scan phase C: per-block exclusive scan of its chunk + block offset;
// writes rowptr AND cursor.
// ---------------------------------------------------------------------------
__global__ __launch_bounds__(256) void scan_final_kernel(
    const int* __restrict__ deg, const int* __restrict__ blockOff,
    int* __restrict__ rowptr, int* __restrict__ cursor, int N) {
  __shared__ int sh[256];
  const int t = threadIdx.x;
  const int idx = blockIdx.x * SCAN_CHUNK + t;
  const int v = (idx < N) ? deg[idx] : 0;
  sh[t] = v;
  __syncthreads();
#pragma unroll
  for (int off = 1; off < 256; off <<= 1) {
    int u = (t >= off) ? sh[t - off] : 0;
    __syncthreads();
    sh[t] += u;
    __syncthreads();
  }
  const int excl = sh[t] - v + blockOff[blockIdx.x];
  if (idx < N) {
    rowptr[idx] = excl;
    cursor[idx] = excl;
    if (idx == N - 1) rowptr[N] = excl + v;
  }
}

// ---------------------------------------------------------------------------
// CSR build step 3: fill column (src) lists using per-node cursors
// ---------------------------------------------------------------------------
__global__ __launch_bounds__(256) void fill_kernel(const int* __restrict__ src,
                                                   const int* __restrict__ dst,
                                                   int* __restrict__ cursor,
                                                   int* __restrict__ col, int E) {
  int e = blockIdx.x * blockDim.x + threadIdx.x;
  if (e >= E) return;
  int pos = atomicAdd(&cursor[dst[e]], 1);
  col[pos] = src[e];
}

// ---------------------------------------------------------------------------
// Row-major x -> chunk-major xT[8][N][16]. XCD-affine: chunk = blockIdx%8, so
// the normal (allocating) store leaves chunk c's 3.2 MB slice warm in XCD c's
// L2 right before aggregate_chunk_kernel reads it. x reads are 64 B strided
// (2x overfetch, nt-hinted, streaming) - cheap vs the L2 warmup it buys.
// ---------------------------------------------------------------------------
__global__ __launch_bounds__(256) void transpose_chunk_kernel(
    const float* __restrict__ x, float* __restrict__ xT, int N) {
  const int c = blockIdx.x & (NCHUNK - 1);
  const int n = (blockIdx.x >> 3) * 64 + (threadIdx.x >> 2);
  const int q4 = (threadIdx.x & 3) * 4;
  if (n >= N) return;
  vfloat4 v = __builtin_nontemporal_load(
      (const vfloat4*)(x + (size_t)n * HIDDEN + c * CH + q4));
  *(vfloat4*)(xT + ((size_t)c * N + n) * CH + q4) = v;
}

// ---------------------------------------------------------------------------
// XCD-affine chunked aggregation (gather):
//   out[n, c*16 .. c*16+16) = xT[c][n][:] + sum_e xT[c][col[e]][:]
// chunk c = blockIdx%8 -> XCD c via round-robin dispatch; per-XCD gather
// working set = N*16*4 = 3.2 MB < 4 MB private L2. col stream and the output
// stream are nt-hinted so they don't evict the resident slice.
// Wave = 16 nodes x 4 lanes (float4 each); each lane accumulates its own
// 16 B slice over its node's edge list (16 independent gather streams/wave).
// ---------------------------------------------------------------------------
__global__ __launch_bounds__(256) void aggregate_chunk_kernel(
    const float* __restrict__ xT, const int* __restrict__ rowptr,
    const int* __restrict__ col, float* __restrict__ out, int N) {
  const int c = blockIdx.x & (NCHUNK - 1);
  const int blk = blockIdx.x >> 3;
  const int t = threadIdx.x;
  const int n = blk * 64 + (t >> 2);
  const int q4 = (t & 3) * 4;
  if (n >= N) return;
  const float* base = xT + (size_t)c * N * CH;
  const int s = rowptr[n];
  const int e = rowptr[n + 1];
  vfloat4 acc = *(const vfloat4*)(base + (size_t)n * CH + q4);  // self term
  int i = s;
  for (; i + 1 < e; i += 2) {
    int c0 = __builtin_nontemporal_load(col + i);
    int c1 = __builtin_nontemporal_load(col + i + 1);
    vfloat4 v0 = *(const vfloat4*)(base + (size_t)c0 * CH + q4);
    vfloat4 v1 = *(const vfloat4*)(base + (size_t)c1 * CH + q4);
    acc += v0;
    acc += v1;
  }
  if (i < e) {
    int c0 = __builtin_nontemporal_load(col + i);
    acc += *(const vfloat4*)(base + (size_t)c0 * CH + q4);
  }
  __builtin_nontemporal_store(
      acc, (vfloat4*)(out + (size_t)n * HIDDEN + c * CH + q4));
}

// ---------------------------------------------------------------------------
// One MLP GEMM pass over K=128: acc[4][4] += xs-tile @ W, W staged in LDS in
// 64-row chunks. Leading __syncthreads protects xs/ws reuse.
// ---------------------------------------------------------------------------
__device__ __forceinline__ void mlp_pass(const float (*xs)[132],
                                         float (*ws)[132],
                                         const float* __restrict__ W, int tx,
                                         int ty, int t, float acc[4][4]) {
  for (int kt = 0; kt < HIDDEN; kt += 64) {
    __syncthreads();
#pragma unroll
    for (int i = 0; i < 8; ++i) {
      int idx = t + i * 256;     // 0..2047
      int r = idx >> 5;          // 0..63
      int c = (idx & 31) * 4;    // 0..124
      *(float4*)&ws[r][c] = *(const float4*)(W + (size_t)(kt + r) * HIDDEN + c);
    }
    __syncthreads();
#pragma unroll
    for (int k = 0; k < 64; k += 4) {
      float av[4][4], wv[4][4];
#pragma unroll
      for (int i = 0; i < 4; ++i) {
        float4 a4 = *(const float4*)&xs[ty * 4 + i][kt + k];
        av[i][0] = a4.x; av[i][1] = a4.y; av[i][2] = a4.z; av[i][3] = a4.w;
      }
#pragma unroll
      for (int kk = 0; kk < 4; ++kk) {
        float4 w4 = *(const float4*)&ws[k + kk][tx * 4];
        wv[kk][0] = w4.x; wv[kk][1] = w4.y; wv[kk][2] = w4.z; wv[kk][3] = w4.w;
      }
#pragma unroll
      for (int i = 0; i < 4; ++i)
#pragma unroll
        for (int kk = 0; kk < 4; ++kk)
#pragma unroll
          for (int j = 0; j < 4; ++j) acc[i][j] += av[i][kk] * wv[kk][j];
    }
  }
}

// ---------------------------------------------------------------------------
// Fused MLP: h2 = relu( relu(A@W1+b1) @ W2 + b2 ) for a 32-row tile.
// h1 lives only in LDS. If doReadout: out[m] = h2[m,:]·Wr + br; else h2->Cout
// either row-major or (outChunk) chunk-major [8][M][16] for the next
// XCD-affine aggregate. Thread grid 32x8. LDS 50.7 KB -> 3 blocks/CU.
// ---------------------------------------------------------------------------
__global__ __launch_bounds__(256) void mlp_kernel(
    const float* __restrict__ A, const float* __restrict__ W1,
    const float* __restrict__ b1, const float* __restrict__ W2,
    const float* __restrict__ b2, float* __restrict__ Cout,
    const float* __restrict__ Wr, const float* __restrict__ br,
    float* __restrict__ outv, int M, int doReadout, int outChunk) {
  __shared__ float xs[32][132];
  __shared__ float ws[64][132];
  const int t = threadIdx.x;
  const int tx = t & 31;
  const int ty = t >> 5;
  const int mBase = blockIdx.x * 32;

  // stage A tile (32 x 128), zero-pad rows past M
#pragma unroll
  for (int i = 0; i < 4; ++i) {
    int idx = t + i * 256;     // 0..1023
    int r = idx >> 5;          // 0..31
    int c = (idx & 31) * 4;
    int gm = mBase + r;
    float4 v = make_float4(0.f, 0.f, 0.f, 0.f);
    if (gm < M) v = *(const float4*)(A + (size_t)gm * HIDDEN + c);
    *(float4*)&xs[r][c] = v;
  }

  float acc[4][4];
#pragma unroll
  for (int i = 0; i < 4; ++i)
#pragma unroll
    for (int j = 0; j < 4; ++j) acc[i][j] = 0.f;

  // MLP1
  mlp_pass(xs, ws, W1, tx, ty, t, acc);

  __syncthreads();  // all reads of xs done before h1 overwrite
  float4 b1v = *(const float4*)(b1 + tx * 4);
#pragma unroll
  for (int i = 0; i < 4; ++i) {
    float4 h;
    h.x = fmaxf(acc[i][0] + b1v.x, 0.f);
    h.y = fmaxf(acc[i][1] + b1v.y, 0.f);
    h.z = fmaxf(acc[i][2] + b1v.z, 0.f);
    h.w = fmaxf(acc[i][3] + b1v.w, 0.f);
    *(float4*)&xs[ty * 4 + i][tx * 4] = h;
    acc[i][0] = acc[i][1] = acc[i][2] = acc[i][3] = 0.f;
  }
  // (mlp_pass's leading barrier makes h1 visible before compute)

  // MLP2
  mlp_pass(xs, ws, W2, tx, ty, t, acc);

  float4 b2v = *(const float4*)(b2 + tx * 4);
  if (!doReadout) {
#pragma unroll
    for (int i = 0; i < 4; ++i) {
      int gm = mBase + ty * 4 + i;
      if (gm >= M) continue;
      float4 o;
      o.x = fmaxf(acc[i][0] + b2v.x, 0.f);
      o.y = fmaxf(acc[i][1] + b2v.y, 0.f);
      o.z = fmaxf(acc[i][2] + b2v.z, 0.f);
      o.w = fmaxf(acc[i][3] + b2v.w, 0.f);
      if (outChunk) {
        // columns tx*4..tx*4+3 -> chunk tx>>2, intra-chunk offset (tx&3)*4
        *(float4*)(Cout + ((size_t)(tx >> 2) * M + gm) * CH + (tx & 3) * 4) = o;
      } else {
        *(float4*)(Cout + (size_t)gm * HIDDEN + tx * 4) = o;
      }
    }
  } else {
    float4 wr = *(const float4*)(Wr + tx * 4);
    float brv = br[0];
#pragma unroll
    for (int i = 0; i < 4; ++i) {
      float h0 = fmaxf(acc[i][0] + b2v.x, 0.f);
      float h1 = fmaxf(acc[i][1] + b2v.y, 0.f);
      float h2 = fmaxf(acc[i][2] + b2v.z, 0.f);
      float h3 = fmaxf(acc[i][3] + b2v.w, 0.f);
      float p = h0 * wr.x + h1 * wr.y + h2 * wr.z + h3 * wr.w;
      // reduce across the 32 tx lanes (xor<32 stays within each half-wave)
      p += __shfl_xor(p, 16);
      p += __shfl_xor(p, 8);
      p += __shfl_xor(p, 4);
      p += __shfl_xor(p, 2);
      p += __shfl_xor(p, 1);
      int gm = mBase + ty * 4 + i;
      if (tx == 0 && gm < M) outv[gm] = p + brv;
    }
  }
}

extern "C" void kernel_launch(void* const* d_in, const int* in_sizes, int n_in,
                              void* d_out, int out_size, void* d_ws,
                              size_t ws_size, hipStream_t stream) {
  const float* x = (const float*)d_in[0];
  const int* ei = (const int*)d_in[1];
  const float* W1_0 = (const float*)d_in[2];
  const float* b1_0 = (const float*)d_in[3];
  const float* W2_0 = (const float*)d_in[4];
  const float* b2_0 = (const float*)d_in[5];
  const float* W1_1 = (const float*)d_in[6];
  const float* b1_1 = (const float*)d_in[7];
  const float* W2_1 = (const float*)d_in[8];
  const float* b2_1 = (const float*)d_in[9];
  const float* Wr = (const float*)d_in[10];
  const float* br = (const float*)d_in[11];

  const int M = in_sizes[0] / HIDDEN;  // 50000 nodes
  const int E = in_sizes[1] / 2;       // 800000 edges
  const int* src = ei;
  const int* dst = ei + E;

  // workspace layout: XT doubles as layer-0 input (chunk-major x) and layer-1
  // input (chunk-major B written by mlp0). A is always the aggregate output.
  float* XT = (float*)d_ws;                   // [8][M][16]
  float* A = XT + (size_t)M * HIDDEN;         // [M,128]
  int* deg = (int*)(A + (size_t)M * HIDDEN);  // [M]
  int* rowptr = deg + M;                      // [M+1]
  int* cursor = rowptr + M + 1;               // [M]
  int* col = cursor + M;                      // [E]
  int* partial = col + E;                     // [256]
  int* blockOff = partial + 256;              // [256]

  const int xcdBlocks = NCHUNK * ((M + 63) / 64);  // chunk = blockIdx % 8
  const int scanBlocks = (M + SCAN_CHUNK - 1) / SCAN_CHUNK;
  const int mlpBlocks = (M + 31) / 32;
  float* out = (float*)d_out;

  // ---- build CSR (dst -> list of src), reused by both layers
  hipMemsetAsync(deg, 0, (size_t)M * sizeof(int), stream);
  hist_kernel<<<(E + 255) / 256, 256, 0, stream>>>(dst, deg, E);
  scan_partial_kernel<<<scanBlocks, 256, 0, stream>>>(deg, partial, M);
  scan_offsets_kernel<<<1, 256, 0, stream>>>(partial, blockOff, scanBlocks);
  scan_final_kernel<<<scanBlocks, 256, 0, stream>>>(deg, blockOff, rowptr,
                                                    cursor, M);
  fill_kernel<<<(E + 255) / 256, 256, 0, stream>>>(src, dst, cursor, col, E);

  // ---- layer 0: transpose -> XCD-affine agg -> fused MLP -> XT (chunk-major)
  transpose_chunk_kernel<<<xcdBlocks, 256, 0, stream>>>(x, XT, M);
  aggregate_chunk_kernel<<<xcdBlocks, 256, 0, stream>>>(XT, rowptr, col, A, M);
  mlp_kernel<<<mlpBlocks, 256, 0, stream>>>(A, W1_0, b1_0, W2_0, b2_0, XT,
                                            nullptr, nullptr, nullptr, M, 0, 1);

  // ---- layer 1: XCD-affine agg -> fused MLP + readout -> out
  aggregate_chunk_kernel<<<xcdBlocks, 256, 0, stream>>>(XT, rowptr, col, A, M);
  mlp_kernel<<<mlpBlocks, 256, 0, stream>>>(A, W1_1, b1_1, W2_1, b2_1, nullptr,
                                            Wr, br, out, M, 1, 0);
}

// Round 2
// 364.822 us; speedup vs baseline: 1.3518x; 1.3518x over previous
//
#include <hip/hip_runtime.h>

#define HIDDEN 128
#define SCAN_CHUNK 256

typedef __attribute__((ext_vector_type(8))) short short8;
typedef __attribute__((ext_vector_type(4))) float f32x4;

// float -> bf16 (RNE), and back
__device__ __forceinline__ ushort f2bf(float a) {
  union { float f; unsigned u; } c; c.f = a;
  return (ushort)((c.u + 0x7FFFu + ((c.u >> 16) & 1u)) >> 16);
}
__device__ __forceinline__ float bf2f(ushort h) {
  union { unsigned u; float f; } c; c.u = ((unsigned)h) << 16;
  return c.f;
}

// ---------------------------------------------------------------------------
// CSR build step 1: degree histogram over dst
// ---------------------------------------------------------------------------
__global__ __launch_bounds__(256) void hist_kernel(const int* __restrict__ dst,
                                                   int* __restrict__ deg, int E) {
  int e = blockIdx.x * blockDim.x + threadIdx.x;
  if (e < E) atomicAdd(&deg[dst[e]], 1);
}

// ---------------------------------------------------------------------------
// CSR scan phase A: per-block chunk sums (chunk = 256 elements, 1/thread)
// ---------------------------------------------------------------------------
__global__ __launch_bounds__(256) void scan_partial_kernel(
    const int* __restrict__ deg, int* __restrict__ partial, int N) {
  __shared__ int red[256];
  const int t = threadIdx.x;
  const int idx = blockIdx.x * SCAN_CHUNK + t;
  red[t] = (idx < N) ? deg[idx] : 0;
  __syncthreads();
#pragma unroll
  for (int off = 128; off; off >>= 1) {
    if (t < off) red[t] += red[t + off];
    __syncthreads();
  }
  if (t == 0) partial[blockIdx.x] = red[0];
}

// ---------------------------------------------------------------------------
// CSR scan phase B: one block scans the (<=256) block partials -> exclusive
// block offsets.
// ---------------------------------------------------------------------------
__global__ __launch_bounds__(256) void scan_offsets_kernel(
    const int* __restrict__ partial, int* __restrict__ blockOff, int nBlocks) {
  __shared__ int sums[256];
  const int t = threadIdx.x;
  const int p = (t < nBlocks) ? partial[t] : 0;
  sums[t] = p;
  __syncthreads();
#pragma unroll
  for (int off = 1; off < 256; off <<= 1) {
    int v = (t >= off) ? sums[t - off] : 0;
    __syncthreads();
    sums[t] += v;
    __syncthreads();
  }
  blockOff[t] = sums[t] - p;  // exclusive
}

// ---------------------------------------------------------------------------
// CSR scan phase C: per-block exclusive scan of its chunk + block offset;
// writes rowptr AND cursor.
// ---------------------------------------------------------------------------
__global__ __launch_bounds__(256) void scan_final_kernel(
    const int* __restrict__ deg, const int* __restrict__ blockOff,
    int* __restrict__ rowptr, int* __restrict__ cursor, int N) {
  __shared__ int sh[256];
  const int t = threadIdx.x;
  const int idx = blockIdx.x * SCAN_CHUNK + t;
  const int v = (idx < N) ? deg[idx] : 0;
  sh[t] = v;
  __syncthreads();
#pragma unroll
  for (int off = 1; off < 256; off <<= 1) {
    int u = (t >= off) ? sh[t - off] : 0;
    __syncthreads();
    sh[t] += u;
    __syncthreads();
  }
  const int excl = sh[t] - v + blockOff[blockIdx.x];
  if (idx < N) {
    rowptr[idx] = excl;
    cursor[idx] = excl;
    if (idx == N - 1) rowptr[N] = excl + v;
  }
}

// ---------------------------------------------------------------------------
// CSR build step 3: fill column (src) lists using per-node cursors
// ---------------------------------------------------------------------------
__global__ __launch_bounds__(256) void fill_kernel(const int* __restrict__ src,
                                                   const int* __restrict__ dst,
                                                   int* __restrict__ cursor,
                                                   int* __restrict__ col, int E) {
  int e = blockIdx.x * blockDim.x + threadIdx.x;
  if (e >= E) return;
  int pos = atomicAdd(&cursor[dst[e]], 1);
  col[pos] = src[e];
}

// ---------------------------------------------------------------------------
// Aggregation as GATHER: out[i,:] = x[i,:] + sum_{e} x[col[e],:]
// One 64-lane wave per node; each lane owns a float2 column slice.
// (R0-proven ~60us; R1's XCD-chunked variant regressed -> reverted.)
// ---------------------------------------------------------------------------
__global__ __launch_bounds__(256) void aggregate_kernel(
    const float* __restrict__ x, const int* __restrict__ rowptr,
    const int* __restrict__ col, float* __restrict__ out, int N) {
  int wid = (int)((blockIdx.x * (size_t)blockDim.x + threadIdx.x) >> 6);
  int lane = threadIdx.x & 63;
  if (wid >= N) return;
  const int s = rowptr[wid];
  const int e = rowptr[wid + 1];
  const int off = lane * 2;
  float2 acc = *(const float2*)(x + (size_t)wid * HIDDEN + off);
  int i = s;
  for (; i + 3 < e; i += 4) {
    int c0 = col[i], c1 = col[i + 1], c2 = col[i + 2], c3 = col[i + 3];
    float2 v0 = *(const float2*)(x + (size_t)c0 * HIDDEN + off);
    float2 v1 = *(const float2*)(x + (size_t)c1 * HIDDEN + off);
    float2 v2 = *(const float2*)(x + (size_t)c2 * HIDDEN + off);
    float2 v3 = *(const float2*)(x + (size_t)c3 * HIDDEN + off);
    acc.x += v0.x + v1.x + v2.x + v3.x;
    acc.y += v0.y + v1.y + v2.y + v3.y;
  }
  for (; i < e; ++i) {
    int c = col[i];
    float2 v = *(const float2*)(x + (size_t)c * HIDDEN + off);
    acc.x += v.x;
    acc.y += v.y;
  }
  *(float2*)(out + (size_t)wid * HIDDEN + off) = acc;
}

// ---------------------------------------------------------------------------
// Prepack all four 128x128 weight matrices into MFMA B-fragment-linear bf16
// hi/lo planes. Fragment mapping (must match the A-side load in mlp_mfma):
//   frag (ks, nf), lane, j  ->  k = ks*32 + (lane>>4)*8 + j, n = nf*16 + (lane&15)
// Because A and B use the SAME (lane,j)->k map inside each mfma call, any
// intra-instruction k-permutation cancels in the dot product.
// Output layout per W: hi[2048][8] then lo[2048][8] ushorts (32 KB + 32 KB).
// ---------------------------------------------------------------------------
__global__ __launch_bounds__(256) void prepack_kernel(
    const float* __restrict__ Wa, const float* __restrict__ Wb,
    const float* __restrict__ Wc, const float* __restrict__ Wd,
    ushort* __restrict__ out) {
  int idx = blockIdx.x * 256 + threadIdx.x;  // 0..8191
  int w = idx >> 11;
  int rem = idx & 2047;
  int ks = rem >> 9;
  int nf = (rem >> 6) & 7;
  int lane = rem & 63;
  const float* W = (w == 0) ? Wa : (w == 1) ? Wb : (w == 2) ? Wc : Wd;
  const int kbase = ks * 32 + (lane >> 4) * 8;
  const int n = nf * 16 + (lane & 15);
  ushort* oh = out + (size_t)w * 32768 + (size_t)rem * 8;
  ushort* ol = oh + 16384;
#pragma unroll
  for (int j = 0; j < 8; ++j) {
    float v = W[(size_t)(kbase + j) * HIDDEN + n];
    ushort h = f2bf(v);
    oh[j] = h;
    ol[j] = f2bf(v - bf2f(h));
  }
}

// ---------------------------------------------------------------------------
// Fused MLP via bf16 split MFMA: h2 = relu( relu(A@W1+b1) @ W2 + b2 ) for a
// 64-row block (4 waves x 16 rows). fp32 inputs split a = ah + al (bf16), 3
// MFMAs per tile (ah*bh, al*bh, ah*bl) -> ~fp32 accuracy at matrix-core rate.
// W fragments stream straight from L2 (prepacked linear); A-frags load
// directly from global; h1 hands off through a wave-PRIVATE LDS tile so the
// kernel needs zero __syncthreads. Epilogue transposes h2 through the same
// tile for coalesced float4 stores, or does the Wr readout in-register.
// LDS 33.8 KB, est ~100 VGPR -> 4 blocks/CU.
// ---------------------------------------------------------------------------
__global__ __launch_bounds__(256) void mlp_mfma_kernel(
    const float* __restrict__ A, const ushort* __restrict__ W1p,
    const float* __restrict__ b1, const ushort* __restrict__ W2p,
    const float* __restrict__ b2, float* __restrict__ Cout,
    const float* __restrict__ Wr, const float* __restrict__ br,
    float* __restrict__ outv, int M, int doReadout) {
  __shared__ float h1[4][16][132];
  const int t = threadIdx.x;
  const int lane = t & 63;
  const int w = t >> 6;
  const int r = lane & 15;     // A row / D col index within fragment
  const int g = lane >> 4;     // k-group / D row group
  const int mBase = blockIdx.x * 64 + w * 16;
  int arow = mBase + r;
  if (arow > M - 1) arow = M - 1;  // clamp: garbage only affects rows >= M

  f32x4 acc[8];
#pragma unroll
  for (int i = 0; i < 8; ++i) acc[i] = (f32x4){0.f, 0.f, 0.f, 0.f};

  // ---- GEMM1: acc[nf] += A[16x128] @ W1[:, nf*16..]
#pragma unroll
  for (int ks = 0; ks < 4; ++ks) {
    const float* ap = A + (size_t)arow * HIDDEN + ks * 32 + g * 8;
    float4 a0 = *(const float4*)ap;
    float4 a1 = *(const float4*)(ap + 4);
    float av[8] = {a0.x, a0.y, a0.z, a0.w, a1.x, a1.y, a1.z, a1.w};
    short8 ah, al;
#pragma unroll
    for (int j = 0; j < 8; ++j) {
      ushort h = f2bf(av[j]);
      ah[j] = (short)h;
      al[j] = (short)f2bf(av[j] - bf2f(h));
    }
#pragma unroll
    for (int nf = 0; nf < 8; ++nf) {
      const ushort* bp = W1p + ((size_t)(ks * 8 + nf) * 64 + lane) * 8;
      short8 bh = *(const short8*)bp;
      short8 bl = *(const short8*)(bp + 16384);
      acc[nf] = __builtin_amdgcn_mfma_f32_16x16x32_bf16(ah, bh, acc[nf], 0, 0, 0);
      acc[nf] = __builtin_amdgcn_mfma_f32_16x16x32_bf16(al, bh, acc[nf], 0, 0, 0);
      acc[nf] = __builtin_amdgcn_mfma_f32_16x16x32_bf16(ah, bl, acc[nf], 0, 0, 0);
    }
  }

  // ---- bias + relu, park h1 in wave-private LDS (C-layout: row=4g+q, col=nf*16+r)
#pragma unroll
  for (int nf = 0; nf < 8; ++nf) {
    float bv = b1[nf * 16 + r];
#pragma unroll
    for (int q = 0; q < 4; ++q)
      h1[w][g * 4 + q][nf * 16 + r] = fmaxf(acc[nf][q] + bv, 0.f);
    acc[nf] = (f32x4){0.f, 0.f, 0.f, 0.f};
  }

  // ---- GEMM2: acc[nf] += h1[16x128] @ W2[:, nf*16..]  (A-frags from LDS)
#pragma unroll
  for (int ks = 0; ks < 4; ++ks) {
    const float* hp = &h1[w][r][ks * 32 + g * 8];
    float4 a0 = *(const float4*)hp;
    float4 a1 = *(const float4*)(hp + 4);
    float av[8] = {a0.x, a0.y, a0.z, a0.w, a1.x, a1.y, a1.z, a1.w};
    short8 ah, al;
#pragma unroll
    for (int j = 0; j < 8; ++j) {
      ushort h = f2bf(av[j]);
      ah[j] = (short)h;
      al[j] = (short)f2bf(av[j] - bf2f(h));
    }
#pragma unroll
    for (int nf = 0; nf < 8; ++nf) {
      const ushort* bp = W2p + ((size_t)(ks * 8 + nf) * 64 + lane) * 8;
      short8 bh = *(const short8*)bp;
      short8 bl = *(const short8*)(bp + 16384);
      acc[nf] = __builtin_amdgcn_mfma_f32_16x16x32_bf16(ah, bh, acc[nf], 0, 0, 0);
      acc[nf] = __builtin_amdgcn_mfma_f32_16x16x32_bf16(al, bh, acc[nf], 0, 0, 0);
      acc[nf] = __builtin_amdgcn_mfma_f32_16x16x32_bf16(ah, bl, acc[nf], 0, 0, 0);
    }
  }

  if (!doReadout) {
    // bias + relu -> LDS (2-way-free writes), then coalesced float4 stores
#pragma unroll
    for (int nf = 0; nf < 8; ++nf) {
      float bv = b2[nf * 16 + r];
#pragma unroll
      for (int q = 0; q < 4; ++q)
        h1[w][g * 4 + q][nf * 16 + r] = fmaxf(acc[nf][q] + bv, 0.f);
    }
    const int rr = lane >> 2;          // 0..15
    const int c0 = (lane & 3) * 32;    // 0,32,64,96
    const int gm = blockIdx.x * 64 + w * 16 + rr;
    if (gm < M) {
#pragma unroll
      for (int i = 0; i < 8; ++i) {
        float4 v = *(const float4*)&h1[w][rr][c0 + i * 4];
        *(float4*)(Cout + (size_t)gm * HIDDEN + c0 + i * 4) = v;
      }
    }
  } else {
    // readout: out[m] = relu(h2)[m,:] . Wr + br, reduced across the 16 r-lanes
    float p[4] = {0.f, 0.f, 0.f, 0.f};
#pragma unroll
    for (int nf = 0; nf < 8; ++nf) {
      float bv = b2[nf * 16 + r];
      float wv = Wr[nf * 16 + r];
#pragma unroll
      for (int q = 0; q < 4; ++q) {
        float h = fmaxf(acc[nf][q] + bv, 0.f);
        p[q] += h * wv;
      }
    }
#pragma unroll
    for (int q = 0; q < 4; ++q) {
      p[q] += __shfl_xor(p[q], 8);
      p[q] += __shfl_xor(p[q], 4);
      p[q] += __shfl_xor(p[q], 2);
      p[q] += __shfl_xor(p[q], 1);
    }
    if (r == 0) {
      float brv = br[0];
#pragma unroll
      for (int q = 0; q < 4; ++q) {
        int gm = mBase + g * 4 + q;
        if (gm < M) outv[gm] = p[q] + brv;
      }
    }
  }
}

extern "C" void kernel_launch(void* const* d_in, const int* in_sizes, int n_in,
                              void* d_out, int out_size, void* d_ws,
                              size_t ws_size, hipStream_t stream) {
  const float* x = (const float*)d_in[0];
  const int* ei = (const int*)d_in[1];
  const float* W1_0 = (const float*)d_in[2];
  const float* b1_0 = (const float*)d_in[3];
  const float* W2_0 = (const float*)d_in[4];
  const float* b2_0 = (const float*)d_in[5];
  const float* W1_1 = (const float*)d_in[6];
  const float* b1_1 = (const float*)d_in[7];
  const float* W2_1 = (const float*)d_in[8];
  const float* b2_1 = (const float*)d_in[9];
  const float* Wr = (const float*)d_in[10];
  const float* br = (const float*)d_in[11];

  const int M = in_sizes[0] / HIDDEN;  // 50000 nodes
  const int E = in_sizes[1] / 2;       // 800000 edges
  const int* src = ei;
  const int* dst = ei + E;

  // workspace layout
  float* A = (float*)d_ws;                   // [M,128] agg output
  float* B = A + (size_t)M * HIDDEN;         // [M,128] layer-0 hidden
  int* deg = (int*)(B + (size_t)M * HIDDEN); // [M]
  int* rowptr = deg + M;                     // [M+1]
  int* cursor = rowptr + M + 1;              // [M]
  int* col = cursor + M;                     // [E]
  int* partial = col + E;                    // [256]
  int* blockOff = partial + 256;             // [256]
  ushort* Wpk = (ushort*)(blockOff + 256);   // 4 x (hi 32KB + lo 32KB)

  const int aggBlocks = (int)(((size_t)M * 64 + 255) / 256);
  const int scanBlocks = (M + SCAN_CHUNK - 1) / SCAN_CHUNK;
  const int mlpBlocks = (M + 63) / 64;
  float* out = (float*)d_out;

  // ---- prepack weights (independent of CSR chain)
  prepack_kernel<<<32, 256, 0, stream>>>(W1_0, W2_0, W1_1, W2_1, Wpk);

  // ---- build CSR (dst -> list of src), reused by both layers
  hipMemsetAsync(deg, 0, (size_t)M * sizeof(int), stream);
  hist_kernel<<<(E + 255) / 256, 256, 0, stream>>>(dst, deg, E);
  scan_partial_kernel<<<scanBlocks, 256, 0, stream>>>(deg, partial, M);
  scan_offsets_kernel<<<1, 256, 0, stream>>>(partial, blockOff, scanBlocks);
  scan_final_kernel<<<scanBlocks, 256, 0, stream>>>(deg, blockOff, rowptr,
                                                    cursor, M);
  fill_kernel<<<(E + 255) / 256, 256, 0, stream>>>(src, dst, cursor, col, E);

  // ---- layer 0: agg -> fused MFMA MLP -> B
  aggregate_kernel<<<aggBlocks, 256, 0, stream>>>(x, rowptr, col, A, M);
  mlp_mfma_kernel<<<mlpBlocks, 256, 0, stream>>>(
      A, Wpk, b1_0, Wpk + 32768, b2_0, B, nullptr, nullptr, nullptr, M, 0);

  // ---- layer 1: agg -> fused MFMA MLP + readout -> out
  aggregate_kernel<<<aggBlocks, 256, 0, stream>>>(B, rowptr, col, A, M);
  mlp_mfma_kernel<<<mlpBlocks, 256, 0, stream>>>(
      A, Wpk + 65536, b1_1, Wpk + 98304, b2_1, nullptr, Wr, br, out, M, 1);
}

// Round 3
// 327.100 us; speedup vs baseline: 1.5077x; 1.1153x over previous
//
#include <hip/hip_runtime.h>

#define HIDDEN 128
#define SCAN_CHUNK 256

typedef __attribute__((ext_vector_type(8))) short short8;
typedef __attribute__((ext_vector_type(4))) float f32x4;
typedef _Float16 f16;
typedef __attribute__((ext_vector_type(2))) _Float16 f16x2;
typedef __attribute__((ext_vector_type(8))) _Float16 f16x8;

// float -> bf16 (RNE), and back
__device__ __forceinline__ ushort f2bf(float a) {
  union { float f; unsigned u; } c; c.f = a;
  return (ushort)((c.u + 0x7FFFu + ((c.u >> 16) & 1u)) >> 16);
}
__device__ __forceinline__ float bf2f(ushort h) {
  union { unsigned u; float f; } c; c.u = ((unsigned)h) << 16;
  return c.f;
}

// ---------------------------------------------------------------------------
// CSR build step 1: degree histogram over dst
// ---------------------------------------------------------------------------
__global__ __launch_bounds__(256) void hist_kernel(const int* __restrict__ dst,
                                                   int* __restrict__ deg, int E) {
  int e = blockIdx.x * blockDim.x + threadIdx.x;
  if (e < E) atomicAdd(&deg[dst[e]], 1);
}

// ---------------------------------------------------------------------------
// CSR scan phase A: per-block chunk sums (chunk = 256 elements, 1/thread)
// ---------------------------------------------------------------------------
__global__ __launch_bounds__(256) void scan_partial_kernel(
    const int* __restrict__ deg, int* __restrict__ partial, int N) {
  __shared__ int red[256];
  const int t = threadIdx.x;
  const int idx = blockIdx.x * SCAN_CHUNK + t;
  red[t] = (idx < N) ? deg[idx] : 0;
  __syncthreads();
#pragma unroll
  for (int off = 128; off; off >>= 1) {
    if (t < off) red[t] += red[t + off];
    __syncthreads();
  }
  if (t == 0) partial[blockIdx.x] = red[0];
}

// ---------------------------------------------------------------------------
// CSR scan phase B: one block scans the (<=256) block partials -> exclusive
// block offsets.
// ---------------------------------------------------------------------------
__global__ __launch_bounds__(256) void scan_offsets_kernel(
    const int* __restrict__ partial, int* __restrict__ blockOff, int nBlocks) {
  __shared__ int sums[256];
  const int t = threadIdx.x;
  const int p = (t < nBlocks) ? partial[t] : 0;
  sums[t] = p;
  __syncthreads();
#pragma unroll
  for (int off = 1; off < 256; off <<= 1) {
    int v = (t >= off) ? sums[t - off] : 0;
    __syncthreads();
    sums[t] += v;
    __syncthreads();
  }
  blockOff[t] = sums[t] - p;  // exclusive
}

// ---------------------------------------------------------------------------
// CSR scan phase C: per-block exclusive scan of its chunk + block offset;
// writes rowptr AND cursor.
// ---------------------------------------------------------------------------
__global__ __launch_bounds__(256) void scan_final_kernel(
    const int* __restrict__ deg, const int* __restrict__ blockOff,
    int* __restrict__ rowptr, int* __restrict__ cursor, int N) {
  __shared__ int sh[256];
  const int t = threadIdx.x;
  const int idx = blockIdx.x * SCAN_CHUNK + t;
  const int v = (idx < N) ? deg[idx] : 0;
  sh[t] = v;
  __syncthreads();
#pragma unroll
  for (int off = 1; off < 256; off <<= 1) {
    int u = (t >= off) ? sh[t - off] : 0;
    __syncthreads();
    sh[t] += u;
    __syncthreads();
  }
  const int excl = sh[t] - v + blockOff[blockIdx.x];
  if (idx < N) {
    rowptr[idx] = excl;
    cursor[idx] = excl;
    if (idx == N - 1) rowptr[N] = excl + v;
  }
}

// ---------------------------------------------------------------------------
// CSR build step 3: fill column (src) lists using per-node cursors
// ---------------------------------------------------------------------------
__global__ __launch_bounds__(256) void fill_kernel(const int* __restrict__ src,
                                                   const int* __restrict__ dst,
                                                   int* __restrict__ cursor,
                                                   int* __restrict__ col, int E) {
  int e = blockIdx.x * blockDim.x + threadIdx.x;
  if (e >= E) return;
  int pos = atomicAdd(&cursor[dst[e]], 1);
  col[pos] = src[e];
}

// ---------------------------------------------------------------------------
// fp32 -> fp16 feature convert (8 elems/thread, 32B in / 16B out per lane)
// ---------------------------------------------------------------------------
__global__ __launch_bounds__(256) void f2h_kernel(const float* __restrict__ in,
                                                  f16* __restrict__ out, int n8) {
  int i = blockIdx.x * 256 + threadIdx.x;
  if (i >= n8) return;
  const float4* p = (const float4*)(in + (size_t)i * 8);
  float4 a = p[0], b = p[1];
  f16x8 o;
  o[0] = (f16)a.x; o[1] = (f16)a.y; o[2] = (f16)a.z; o[3] = (f16)a.w;
  o[4] = (f16)b.x; o[5] = (f16)b.y; o[6] = (f16)b.z; o[7] = (f16)b.w;
  *(f16x8*)(out + (size_t)i * 8) = o;
}

// ---------------------------------------------------------------------------
// Aggregation as GATHER over fp16 rows: out[i,:] = x[i,:] + sum_e x[col[e],:]
// One 64-lane wave per node; each lane owns 2 columns (4 B/edge). Row = 256 B
// (half of R2's fp32 512 B) -> halves the L2-miss gather stream that was the
// R2 bottleneck (FETCH 185 MB @ 3.6 TB/s). Accumulate fp32, output fp32.
// ---------------------------------------------------------------------------
__global__ __launch_bounds__(256) void aggregate_kernel(
    const f16* __restrict__ xh, const int* __restrict__ rowptr,
    const int* __restrict__ col, float* __restrict__ out, int N) {
  int wid = (int)((blockIdx.x * (size_t)blockDim.x + threadIdx.x) >> 6);
  int lane = threadIdx.x & 63;
  if (wid >= N) return;
  const int s = rowptr[wid];
  const int e = rowptr[wid + 1];
  const int off = lane * 2;
  f16x2 sv = *(const f16x2*)(xh + (size_t)wid * HIDDEN + off);
  float2 acc = make_float2((float)sv.x, (float)sv.y);
  int i = s;
  for (; i + 3 < e; i += 4) {
    int c0 = col[i], c1 = col[i + 1], c2 = col[i + 2], c3 = col[i + 3];
    f16x2 v0 = *(const f16x2*)(xh + (size_t)c0 * HIDDEN + off);
    f16x2 v1 = *(const f16x2*)(xh + (size_t)c1 * HIDDEN + off);
    f16x2 v2 = *(const f16x2*)(xh + (size_t)c2 * HIDDEN + off);
    f16x2 v3 = *(const f16x2*)(xh + (size_t)c3 * HIDDEN + off);
    acc.x += (float)v0.x + (float)v1.x + (float)v2.x + (float)v3.x;
    acc.y += (float)v0.y + (float)v1.y + (float)v2.y + (float)v3.y;
  }
  for (; i < e; ++i) {
    int c = col[i];
    f16x2 v = *(const f16x2*)(xh + (size_t)c * HIDDEN + off);
    acc.x += (float)v.x;
    acc.y += (float)v.y;
  }
  *(float2*)(out + (size_t)wid * HIDDEN + off) = acc;
}

// ---------------------------------------------------------------------------
// Prepack all four 128x128 weight matrices into MFMA B-fragment-linear bf16
// hi/lo planes. Fragment mapping (must match the A-side load in mlp_mfma):
//   frag (ks, nf), lane, j  ->  k = ks*32 + (lane>>4)*8 + j, n = nf*16 + (lane&15)
// ---------------------------------------------------------------------------
__global__ __launch_bounds__(256) void prepack_kernel(
    const float* __restrict__ Wa, const float* __restrict__ Wb,
    const float* __restrict__ Wc, const float* __restrict__ Wd,
    ushort* __restrict__ out) {
  int idx = blockIdx.x * 256 + threadIdx.x;  // 0..8191
  int w = idx >> 11;
  int rem = idx & 2047;
  int ks = rem >> 9;
  int nf = (rem >> 6) & 7;
  int lane = rem & 63;
  const float* W = (w == 0) ? Wa : (w == 1) ? Wb : (w == 2) ? Wc : Wd;
  const int kbase = ks * 32 + (lane >> 4) * 8;
  const int n = nf * 16 + (lane & 15);
  ushort* oh = out + (size_t)w * 32768 + (size_t)rem * 8;
  ushort* ol = oh + 16384;
#pragma unroll
  for (int j = 0; j < 8; ++j) {
    float v = W[(size_t)(kbase + j) * HIDDEN + n];
    ushort h = f2bf(v);
    oh[j] = h;
    ol[j] = f2bf(v - bf2f(h));
  }
}

// ---------------------------------------------------------------------------
// Fused MLP via bf16 split MFMA: h2 = relu( relu(A@W1+b1) @ W2 + b2 ) for a
// 64-row block (4 waves x 16 rows). fp32 inputs split a = ah + al (bf16), 3
// MFMAs per tile -> ~fp32 accuracy at matrix-core rate. Zero __syncthreads
// (wave-private LDS tile). If !doReadout: h2 stored as fp16 (next layer's
// gather input). If doReadout: in-register Wr dot + shuffle reduce.
// ---------------------------------------------------------------------------
__global__ __launch_bounds__(256) void mlp_mfma_kernel(
    const float* __restrict__ A, const ushort* __restrict__ W1p,
    const float* __restrict__ b1, const ushort* __restrict__ W2p,
    const float* __restrict__ b2, f16* __restrict__ Ch,
    const float* __restrict__ Wr, const float* __restrict__ br,
    float* __restrict__ outv, int M, int doReadout) {
  __shared__ float h1[4][16][132];
  const int t = threadIdx.x;
  const int lane = t & 63;
  const int w = t >> 6;
  const int r = lane & 15;     // A row / D col index within fragment
  const int g = lane >> 4;     // k-group / D row group
  const int mBase = blockIdx.x * 64 + w * 16;
  int arow = mBase + r;
  if (arow > M - 1) arow = M - 1;  // clamp: garbage only affects rows >= M

  f32x4 acc[8];
#pragma unroll
  for (int i = 0; i < 8; ++i) acc[i] = (f32x4){0.f, 0.f, 0.f, 0.f};

  // ---- GEMM1: acc[nf] += A[16x128] @ W1[:, nf*16..]
#pragma unroll
  for (int ks = 0; ks < 4; ++ks) {
    const float* ap = A + (size_t)arow * HIDDEN + ks * 32 + g * 8;
    float4 a0 = *(const float4*)ap;
    float4 a1 = *(const float4*)(ap + 4);
    float av[8] = {a0.x, a0.y, a0.z, a0.w, a1.x, a1.y, a1.z, a1.w};
    short8 ah, al;
#pragma unroll
    for (int j = 0; j < 8; ++j) {
      ushort h = f2bf(av[j]);
      ah[j] = (short)h;
      al[j] = (short)f2bf(av[j] - bf2f(h));
    }
#pragma unroll
    for (int nf = 0; nf < 8; ++nf) {
      const ushort* bp = W1p + ((size_t)(ks * 8 + nf) * 64 + lane) * 8;
      short8 bh = *(const short8*)bp;
      short8 bl = *(const short8*)(bp + 16384);
      acc[nf] = __builtin_amdgcn_mfma_f32_16x16x32_bf16(ah, bh, acc[nf], 0, 0, 0);
      acc[nf] = __builtin_amdgcn_mfma_f32_16x16x32_bf16(al, bh, acc[nf], 0, 0, 0);
      acc[nf] = __builtin_amdgcn_mfma_f32_16x16x32_bf16(ah, bl, acc[nf], 0, 0, 0);
    }
  }

  // ---- bias + relu, park h1 in wave-private LDS (C-layout: row=4g+q, col=nf*16+r)
#pragma unroll
  for (int nf = 0; nf < 8; ++nf) {
    float bv = b1[nf * 16 + r];
#pragma unroll
    for (int q = 0; q < 4; ++q)
      h1[w][g * 4 + q][nf * 16 + r] = fmaxf(acc[nf][q] + bv, 0.f);
    acc[nf] = (f32x4){0.f, 0.f, 0.f, 0.f};
  }

  // ---- GEMM2: acc[nf] += h1[16x128] @ W2[:, nf*16..]  (A-frags from LDS)
#pragma unroll
  for (int ks = 0; ks < 4; ++ks) {
    const float* hp = &h1[w][r][ks * 32 + g * 8];
    float4 a0 = *(const float4*)hp;
    float4 a1 = *(const float4*)(hp + 4);
    float av[8] = {a0.x, a0.y, a0.z, a0.w, a1.x, a1.y, a1.z, a1.w};
    short8 ah, al;
#pragma unroll
    for (int j = 0; j < 8; ++j) {
      ushort h = f2bf(av[j]);
      ah[j] = (short)h;
      al[j] = (short)f2bf(av[j] - bf2f(h));
    }
#pragma unroll
    for (int nf = 0; nf < 8; ++nf) {
      const ushort* bp = W2p + ((size_t)(ks * 8 + nf) * 64 + lane) * 8;
      short8 bh = *(const short8*)bp;
      short8 bl = *(const short8*)(bp + 16384);
      acc[nf] = __builtin_amdgcn_mfma_f32_16x16x32_bf16(ah, bh, acc[nf], 0, 0, 0);
      acc[nf] = __builtin_amdgcn_mfma_f32_16x16x32_bf16(al, bh, acc[nf], 0, 0, 0);
      acc[nf] = __builtin_amdgcn_mfma_f32_16x16x32_bf16(ah, bl, acc[nf], 0, 0, 0);
    }
  }

  if (!doReadout) {
    // bias + relu -> LDS, then coalesced fp16 stores (halves layer-0 writes)
#pragma unroll
    for (int nf = 0; nf < 8; ++nf) {
      float bv = b2[nf * 16 + r];
#pragma unroll
      for (int q = 0; q < 4; ++q)
        h1[w][g * 4 + q][nf * 16 + r] = fmaxf(acc[nf][q] + bv, 0.f);
    }
    const int rr = lane >> 2;          // 0..15
    const int c0 = (lane & 3) * 32;    // 0,32,64,96
    const int gm = blockIdx.x * 64 + w * 16 + rr;
    if (gm < M) {
#pragma unroll
      for (int i = 0; i < 4; ++i) {
        float4 v0 = *(const float4*)&h1[w][rr][c0 + i * 8];
        float4 v1 = *(const float4*)&h1[w][rr][c0 + i * 8 + 4];
        f16x8 o;
        o[0] = (f16)v0.x; o[1] = (f16)v0.y; o[2] = (f16)v0.z; o[3] = (f16)v0.w;
        o[4] = (f16)v1.x; o[5] = (f16)v1.y; o[6] = (f16)v1.z; o[7] = (f16)v1.w;
        *(f16x8*)(Ch + (size_t)gm * HIDDEN + c0 + i * 8) = o;
      }
    }
  } else {
    // readout: out[m] = relu(h2)[m,:] . Wr + br, reduced across the 16 r-lanes
    float p[4] = {0.f, 0.f, 0.f, 0.f};
#pragma unroll
    for (int nf = 0; nf < 8; ++nf) {
      float bv = b2[nf * 16 + r];
      float wv = Wr[nf * 16 + r];
#pragma unroll
      for (int q = 0; q < 4; ++q) {
        float h = fmaxf(acc[nf][q] + bv, 0.f);
        p[q] += h * wv;
      }
    }
#pragma unroll
    for (int q = 0; q < 4; ++q) {
      p[q] += __shfl_xor(p[q], 8);
      p[q] += __shfl_xor(p[q], 4);
      p[q] += __shfl_xor(p[q], 2);
      p[q] += __shfl_xor(p[q], 1);
    }
    if (r == 0) {
      float brv = br[0];
#pragma unroll
      for (int q = 0; q < 4; ++q) {
        int gm = mBase + g * 4 + q;
        if (gm < M) outv[gm] = p[q] + brv;
      }
    }
  }
}

extern "C" void kernel_launch(void* const* d_in, const int* in_sizes, int n_in,
                              void* d_out, int out_size, void* d_ws,
                              size_t ws_size, hipStream_t stream) {
  const float* x = (const float*)d_in[0];
  const int* ei = (const int*)d_in[1];
  const float* W1_0 = (const float*)d_in[2];
  const float* b1_0 = (const float*)d_in[3];
  const float* W2_0 = (const float*)d_in[4];
  const float* b2_0 = (const float*)d_in[5];
  const float* W1_1 = (const float*)d_in[6];
  const float* b1_1 = (const float*)d_in[7];
  const float* W2_1 = (const float*)d_in[8];
  const float* b2_1 = (const float*)d_in[9];
  const float* Wr = (const float*)d_in[10];
  const float* br = (const float*)d_in[11];

  const int M = in_sizes[0] / HIDDEN;  // 50000 nodes
  const int E = in_sizes[1] / 2;       // 800000 edges
  const int* src = ei;
  const int* dst = ei + E;

  // workspace layout
  float* A = (float*)d_ws;                   // [M,128] fp32 agg output
  f16* xh = (f16*)(A + (size_t)M * HIDDEN);  // [M,128] fp16 features
  f16* Bh = xh + (size_t)M * HIDDEN;         // [M,128] fp16 layer-0 hidden
  int* deg = (int*)(Bh + (size_t)M * HIDDEN);// [M]
  int* rowptr = deg + M;                     // [M+1]
  int* cursor = rowptr + M + 1;              // [M]
  int* col = cursor + M;                     // [E]
  int* partial = col + E;                    // [256]
  int* blockOff = partial + 256;             // [256]
  ushort* Wpk = (ushort*)(blockOff + 256);   // 4 x (hi 32KB + lo 32KB)

  const int aggBlocks = (int)(((size_t)M * 64 + 255) / 256);
  const int scanBlocks = (M + SCAN_CHUNK - 1) / SCAN_CHUNK;
  const int mlpBlocks = (M + 63) / 64;
  const int cvtBlocks = (M * 16 + 255) / 256;  // M*128/8 threads
  float* out = (float*)d_out;

  // ---- prepack weights + fp16 feature copy (independent of CSR chain)
  prepack_kernel<<<32, 256, 0, stream>>>(W1_0, W2_0, W1_1, W2_1, Wpk);
  f2h_kernel<<<cvtBlocks, 256, 0, stream>>>(x, xh, M * 16);

  // ---- build CSR (dst -> list of src), reused by both layers
  hipMemsetAsync(deg, 0, (size_t)M * sizeof(int), stream);
  hist_kernel<<<(E + 255) / 256, 256, 0, stream>>>(dst, deg, E);
  scan_partial_kernel<<<scanBlocks, 256, 0, stream>>>(deg, partial, M);
  scan_offsets_kernel<<<1, 256, 0, stream>>>(partial, blockOff, scanBlocks);
  scan_final_kernel<<<scanBlocks, 256, 0, stream>>>(deg, blockOff, rowptr,
                                                    cursor, M);
  fill_kernel<<<(E + 255) / 256, 256, 0, stream>>>(src, dst, cursor, col, E);

  // ---- layer 0: agg(fp16 x) -> fused MFMA MLP -> Bh (fp16)
  aggregate_kernel<<<aggBlocks, 256, 0, stream>>>(xh, rowptr, col, A, M);
  mlp_mfma_kernel<<<mlpBlocks, 256, 0, stream>>>(
      A, Wpk, b1_0, Wpk + 32768, b2_0, Bh, nullptr, nullptr, nullptr, M, 0);

  // ---- layer 1: agg(fp16 Bh) -> fused MFMA MLP + readout -> out
  aggregate_kernel<<<aggBlocks, 256, 0, stream>>>(Bh, rowptr, col, A, M);
  mlp_mfma_kernel<<<mlpBlocks, 256, 0, stream>>>(
      A, Wpk + 65536, b1_1, Wpk + 98304, b2_1, nullptr, Wr, br, out, M, 1);
}

// Round 4
// 284.611 us; speedup vs baseline: 1.7328x; 1.1493x over previous
//
#include <hip/hip_runtime.h>

#define HIDDEN 128
#define NB_SHIFT 7            // 128 dst nodes per bucket
#define NPB 128               // nodes per bucket
#define EPB 4096              // edges per partition/hist block

typedef __attribute__((ext_vector_type(8))) short short8;
typedef __attribute__((ext_vector_type(4))) float f32x4;
typedef _Float16 f16;
typedef __attribute__((ext_vector_type(2))) _Float16 f16x2;
typedef __attribute__((ext_vector_type(8))) _Float16 f16x8;

// float -> bf16 (RNE), and back
__device__ __forceinline__ ushort f2bf(float a) {
  union { float f; unsigned u; } c; c.f = a;
  return (ushort)((c.u + 0x7FFFu + ((c.u >> 16) & 1u)) >> 16);
}
__device__ __forceinline__ float bf2f(ushort h) {
  union { unsigned u; float f; } c; c.u = ((unsigned)h) << 16;
  return c.f;
}

// ---------------------------------------------------------------------------
// CSR build A: per-bucket edge histogram (LDS-local, then merge).
// Replaces the old per-node hist: 400 counters instead of 50k, merged once
// per block -> trivial atomic traffic.
// ---------------------------------------------------------------------------
__global__ __launch_bounds__(256) void bucket_hist_kernel(
    const int* __restrict__ dst, int* __restrict__ bcnt, int E, int NB) {
  __shared__ int loc[512];
  const int t = threadIdx.x;
  loc[t] = 0; loc[t + 256] = 0;
  __syncthreads();
  const int base = blockIdx.x * EPB;
  const int end = min(base + EPB, E);
  for (int e = base + t; e < end; e += 256)
    atomicAdd(&loc[dst[e] >> NB_SHIFT], 1);
  __syncthreads();
  for (int b = t; b < NB; b += 256)
    if (loc[b]) atomicAdd(&bcnt[b], loc[b]);
}

// ---------------------------------------------------------------------------
// CSR build B: exclusive scan of <=512 bucket counts -> pairOff (ranges) and
// gCursor (mutable copy for the partition pass). pairOff[NB] = E.
// ---------------------------------------------------------------------------
__global__ __launch_bounds__(256) void scan_buckets_kernel(
    const int* __restrict__ bcnt, int* __restrict__ pairOff,
    int* __restrict__ gCursor, int NB) {
  __shared__ int sh[512];
  const int t = threadIdx.x;
  const int v0 = (t < NB) ? bcnt[t] : 0;
  const int v1 = (t + 256 < NB) ? bcnt[t + 256] : 0;
  sh[t] = v0; sh[t + 256] = v1;
  __syncthreads();
#pragma unroll
  for (int off = 1; off < 512; off <<= 1) {
    int a = (t >= off) ? sh[t - off] : 0;
    int b = (t + 256 >= off) ? sh[t + 256 - off] : 0;
    __syncthreads();
    sh[t] += a; sh[t + 256] += b;
    __syncthreads();
  }
  const int e0 = sh[t] - v0;        // exclusive
  const int e1 = sh[t + 256] - v1;
  pairOff[t] = e0; gCursor[t] = e0;
  pairOff[t + 256] = e1; gCursor[t + 256] = e1;
  if (t == 255) pairOff[512] = sh[511];
}

// ---------------------------------------------------------------------------
// CSR build C: partition edges into bucket-contiguous (src,dst) pairs.
// Per block: LDS bucket hist of its 4096-edge chunk, ONE global atomic per
// touched bucket to reserve contiguous space, then append via LDS cursors.
// Each bucket tail line stays hot (active write set ~0.6 MB/XCD), so HBM
// writes ~ pair bytes (10-15 MB), not edges x 64 B (the old fill's 52 MB).
// ---------------------------------------------------------------------------
__global__ __launch_bounds__(256) void partition_kernel(
    const int* __restrict__ src, const int* __restrict__ dst,
    int* __restrict__ gCursor, int2* __restrict__ pairs, int E, int NB) {
  __shared__ int loc[512];
  __shared__ int cur[512];
  const int t = threadIdx.x;
  loc[t] = 0; loc[t + 256] = 0;
  __syncthreads();
  const int base = blockIdx.x * EPB;
  const int end = min(base + EPB, E);
  for (int e = base + t; e < end; e += 256)
    atomicAdd(&loc[dst[e] >> NB_SHIFT], 1);
  __syncthreads();
  for (int b = t; b < NB; b += 256)
    cur[b] = loc[b] ? atomicAdd(&gCursor[b], loc[b]) : 0;
  __syncthreads();
  for (int e = base + t; e < end; e += 256) {
    const int d = dst[e];
    const int p = atomicAdd(&cur[d >> NB_SHIFT], 1);
    pairs[p] = make_int2(src[e], d);
  }
}

// ---------------------------------------------------------------------------
// CSR build D: one block per bucket. LDS degree hist of the bucket's edges,
// local scan -> rowptr (dense 512 B write) + in-bucket placement of col
// (dense 16 KB region, L2-resident). Replaces the global deg scan + fill.
// ---------------------------------------------------------------------------
__global__ __launch_bounds__(256) void build_csr_kernel(
    const int2* __restrict__ pairs, const int* __restrict__ pairOff,
    int* __restrict__ rowptr, int* __restrict__ col, int M, int E, int NB) {
  __shared__ int deg[NPB];
  __shared__ int pre[NPB];
  __shared__ int cur[NPB];
  const int b = blockIdx.x;
  const int t = threadIdx.x;
  const int s = pairOff[b];
  const int e2 = pairOff[b + 1];
  const int nodeBase = b << NB_SHIFT;
  const int nNodes = min(NPB, M - nodeBase);
  if (t < NPB) deg[t] = 0;
  __syncthreads();
  for (int i = s + t; i < e2; i += 256)
    atomicAdd(&deg[pairs[i].y & (NPB - 1)], 1);
  __syncthreads();
  if (t < NPB) pre[t] = deg[t];
  __syncthreads();
#pragma unroll
  for (int off = 1; off < NPB; off <<= 1) {
    int v = (t < NPB && t >= off) ? pre[t - off] : 0;
    __syncthreads();
    if (t < NPB) pre[t] += v;
    __syncthreads();
  }
  // pre = inclusive; exclusive = pre - deg
  if (t < nNodes) rowptr[nodeBase + t] = s + pre[t] - deg[t];
  if (b == NB - 1 && t == 0) rowptr[M] = E;
  if (t < NPB) cur[t] = pre[t] - deg[t];
  __syncthreads();
  for (int i = s + t; i < e2; i += 256) {
    const int2 pr = pairs[i];
    const int pos = s + atomicAdd(&cur[pr.y & (NPB - 1)], 1);
    col[pos] = pr.x;
  }
}

// ---------------------------------------------------------------------------
// fp32 -> fp16 feature convert (8 elems/thread, 32B in / 16B out per lane)
// ---------------------------------------------------------------------------
__global__ __launch_bounds__(256) void f2h_kernel(const float* __restrict__ in,
                                                  f16* __restrict__ out, int n8) {
  int i = blockIdx.x * 256 + threadIdx.x;
  if (i >= n8) return;
  const float4* p = (const float4*)(in + (size_t)i * 8);
  float4 a = p[0], b = p[1];
  f16x8 o;
  o[0] = (f16)a.x; o[1] = (f16)a.y; o[2] = (f16)a.z; o[3] = (f16)a.w;
  o[4] = (f16)b.x; o[5] = (f16)b.y; o[6] = (f16)b.z; o[7] = (f16)b.w;
  *(f16x8*)(out + (size_t)i * 8) = o;
}

// ---------------------------------------------------------------------------
// Aggregation as GATHER over fp16 rows: out[i,:] = x[i,:] + sum_e x[col[e],:]
// One 64-lane wave per node; each lane owns 2 columns (4 B/edge).
// ---------------------------------------------------------------------------
__global__ __launch_bounds__(256) void aggregate_kernel(
    const f16* __restrict__ xh, const int* __restrict__ rowptr,
    const int* __restrict__ col, float* __restrict__ out, int N) {
  int wid = (int)((blockIdx.x * (size_t)blockDim.x + threadIdx.x) >> 6);
  int lane = threadIdx.x & 63;
  if (wid >= N) return;
  const int s = rowptr[wid];
  const int e = rowptr[wid + 1];
  const int off = lane * 2;
  f16x2 sv = *(const f16x2*)(xh + (size_t)wid * HIDDEN + off);
  float2 acc = make_float2((float)sv.x, (float)sv.y);
  int i = s;
  for (; i + 3 < e; i += 4) {
    int c0 = col[i], c1 = col[i + 1], c2 = col[i + 2], c3 = col[i + 3];
    f16x2 v0 = *(const f16x2*)(xh + (size_t)c0 * HIDDEN + off);
    f16x2 v1 = *(const f16x2*)(xh + (size_t)c1 * HIDDEN + off);
    f16x2 v2 = *(const f16x2*)(xh + (size_t)c2 * HIDDEN + off);
    f16x2 v3 = *(const f16x2*)(xh + (size_t)c3 * HIDDEN + off);
    acc.x += (float)v0.x + (float)v1.x + (float)v2.x + (float)v3.x;
    acc.y += (float)v0.y + (float)v1.y + (float)v2.y + (float)v3.y;
  }
  for (; i < e; ++i) {
    int c = col[i];
    f16x2 v = *(const f16x2*)(xh + (size_t)c * HIDDEN + off);
    acc.x += (float)v.x;
    acc.y += (float)v.y;
  }
  *(float2*)(out + (size_t)wid * HIDDEN + off) = acc;
}

// ---------------------------------------------------------------------------
// Prepack all four 128x128 weight matrices into MFMA B-fragment-linear bf16
// hi/lo planes. Fragment mapping (must match the A-side load in mlp_mfma):
//   frag (ks, nf), lane, j  ->  k = ks*32 + (lane>>4)*8 + j, n = nf*16 + (lane&15)
// ---------------------------------------------------------------------------
__global__ __launch_bounds__(256) void prepack_kernel(
    const float* __restrict__ Wa, const float* __restrict__ Wb,
    const float* __restrict__ Wc, const float* __restrict__ Wd,
    ushort* __restrict__ out) {
  int idx = blockIdx.x * 256 + threadIdx.x;  // 0..8191
  int w = idx >> 11;
  int rem = idx & 2047;
  int ks = rem >> 9;
  int nf = (rem >> 6) & 7;
  int lane = rem & 63;
  const float* W = (w == 0) ? Wa : (w == 1) ? Wb : (w == 2) ? Wc : Wd;
  const int kbase = ks * 32 + (lane >> 4) * 8;
  const int n = nf * 16 + (lane & 15);
  ushort* oh = out + (size_t)w * 32768 + (size_t)rem * 8;
  ushort* ol = oh + 16384;
#pragma unroll
  for (int j = 0; j < 8; ++j) {
    float v = W[(size_t)(kbase + j) * HIDDEN + n];
    ushort h = f2bf(v);
    oh[j] = h;
    ol[j] = f2bf(v - bf2f(h));
  }
}

// ---------------------------------------------------------------------------
// Fused MLP via bf16 split MFMA: h2 = relu( relu(A@W1+b1) @ W2 + b2 ) for a
// 64-row block (4 waves x 16 rows). fp32 inputs split a = ah + al (bf16), 3
// MFMAs per tile -> ~fp32 accuracy at matrix-core rate. Zero __syncthreads
// (wave-private LDS tile). If !doReadout: h2 stored as fp16 (next layer's
// gather input). If doReadout: in-register Wr dot + shuffle reduce.
// ---------------------------------------------------------------------------
__global__ __launch_bounds__(256) void mlp_mfma_kernel(
    const float* __restrict__ A, const ushort* __restrict__ W1p,
    const float* __restrict__ b1, const ushort* __restrict__ W2p,
    const float* __restrict__ b2, f16* __restrict__ Ch,
    const float* __restrict__ Wr, const float* __restrict__ br,
    float* __restrict__ outv, int M, int doReadout) {
  __shared__ float h1[4][16][132];
  const int t = threadIdx.x;
  const int lane = t & 63;
  const int w = t >> 6;
  const int r = lane & 15;     // A row / D col index within fragment
  const int g = lane >> 4;     // k-group / D row group
  const int mBase = blockIdx.x * 64 + w * 16;
  int arow = mBase + r;
  if (arow > M - 1) arow = M - 1;  // clamp: garbage only affects rows >= M

  f32x4 acc[8];
#pragma unroll
  for (int i = 0; i < 8; ++i) acc[i] = (f32x4){0.f, 0.f, 0.f, 0.f};

  // ---- GEMM1: acc[nf] += A[16x128] @ W1[:, nf*16..]
#pragma unroll
  for (int ks = 0; ks < 4; ++ks) {
    const float* ap = A + (size_t)arow * HIDDEN + ks * 32 + g * 8;
    float4 a0 = *(const float4*)ap;
    float4 a1 = *(const float4*)(ap + 4);
    float av[8] = {a0.x, a0.y, a0.z, a0.w, a1.x, a1.y, a1.z, a1.w};
    short8 ah, al;
#pragma unroll
    for (int j = 0; j < 8; ++j) {
      ushort h = f2bf(av[j]);
      ah[j] = (short)h;
      al[j] = (short)f2bf(av[j] - bf2f(h));
    }
#pragma unroll
    for (int nf = 0; nf < 8; ++nf) {
      const ushort* bp = W1p + ((size_t)(ks * 8 + nf) * 64 + lane) * 8;
      short8 bh = *(const short8*)bp;
      short8 bl = *(const short8*)(bp + 16384);
      acc[nf] = __builtin_amdgcn_mfma_f32_16x16x32_bf16(ah, bh, acc[nf], 0, 0, 0);
      acc[nf] = __builtin_amdgcn_mfma_f32_16x16x32_bf16(al, bh, acc[nf], 0, 0, 0);
      acc[nf] = __builtin_amdgcn_mfma_f32_16x16x32_bf16(ah, bl, acc[nf], 0, 0, 0);
    }
  }

  // ---- bias + relu, park h1 in wave-private LDS (C-layout: row=4g+q, col=nf*16+r)
#pragma unroll
  for (int nf = 0; nf < 8; ++nf) {
    float bv = b1[nf * 16 + r];
#pragma unroll
    for (int q = 0; q < 4; ++q)
      h1[w][g * 4 + q][nf * 16 + r] = fmaxf(acc[nf][q] + bv, 0.f);
    acc[nf] = (f32x4){0.f, 0.f, 0.f, 0.f};
  }

  // ---- GEMM2: acc[nf] += h1[16x128] @ W2[:, nf*16..]  (A-frags from LDS)
#pragma unroll
  for (int ks = 0; ks < 4; ++ks) {
    const float* hp = &h1[w][r][ks * 32 + g * 8];
    float4 a0 = *(const float4*)hp;
    float4 a1 = *(const float4*)(hp + 4);
    float av[8] = {a0.x, a0.y, a0.z, a0.w, a1.x, a1.y, a1.z, a1.w};
    short8 ah, al;
#pragma unroll
    for (int j = 0; j < 8; ++j) {
      ushort h = f2bf(av[j]);
      ah[j] = (short)h;
      al[j] = (short)f2bf(av[j] - bf2f(h));
    }
#pragma unroll
    for (int nf = 0; nf < 8; ++nf) {
      const ushort* bp = W2p + ((size_t)(ks * 8 + nf) * 64 + lane) * 8;
      short8 bh = *(const short8*)bp;
      short8 bl = *(const short8*)(bp + 16384);
      acc[nf] = __builtin_amdgcn_mfma_f32_16x16x32_bf16(ah, bh, acc[nf], 0, 0, 0);
      acc[nf] = __builtin_amdgcn_mfma_f32_16x16x32_bf16(al, bh, acc[nf], 0, 0, 0);
      acc[nf] = __builtin_amdgcn_mfma_f32_16x16x32_bf16(ah, bl, acc[nf], 0, 0, 0);
    }
  }

  if (!doReadout) {
    // bias + relu -> LDS, then coalesced fp16 stores (halves layer-0 writes)
#pragma unroll
    for (int nf = 0; nf < 8; ++nf) {
      float bv = b2[nf * 16 + r];
#pragma unroll
      for (int q = 0; q < 4; ++q)
        h1[w][g * 4 + q][nf * 16 + r] = fmaxf(acc[nf][q] + bv, 0.f);
    }
    const int rr = lane >> 2;          // 0..15
    const int c0 = (lane & 3) * 32;    // 0,32,64,96
    const int gm = blockIdx.x * 64 + w * 16 + rr;
    if (gm < M) {
#pragma unroll
      for (int i = 0; i < 4; ++i) {
        float4 v0 = *(const float4*)&h1[w][rr][c0 + i * 8];
        float4 v1 = *(const float4*)&h1[w][rr][c0 + i * 8 + 4];
        f16x8 o;
        o[0] = (f16)v0.x; o[1] = (f16)v0.y; o[2] = (f16)v0.z; o[3] = (f16)v0.w;
        o[4] = (f16)v1.x; o[5] = (f16)v1.y; o[6] = (f16)v1.z; o[7] = (f16)v1.w;
        *(f16x8*)(Ch + (size_t)gm * HIDDEN + c0 + i * 8) = o;
      }
    }
  } else {
    // readout: out[m] = relu(h2)[m,:] . Wr + br, reduced across the 16 r-lanes
    float p[4] = {0.f, 0.f, 0.f, 0.f};
#pragma unroll
    for (int nf = 0; nf < 8; ++nf) {
      float bv = b2[nf * 16 + r];
      float wv = Wr[nf * 16 + r];
#pragma unroll
      for (int q = 0; q < 4; ++q) {
        float h = fmaxf(acc[nf][q] + bv, 0.f);
        p[q] += h * wv;
      }
    }
#pragma unroll
    for (int q = 0; q < 4; ++q) {
      p[q] += __shfl_xor(p[q], 8);
      p[q] += __shfl_xor(p[q], 4);
      p[q] += __shfl_xor(p[q], 2);
      p[q] += __shfl_xor(p[q], 1);
    }
    if (r == 0) {
      float brv = br[0];
#pragma unroll
      for (int q = 0; q < 4; ++q) {
        int gm = mBase + g * 4 + q;
        if (gm < M) outv[gm] = p[q] + brv;
      }
    }
  }
}

extern "C" void kernel_launch(void* const* d_in, const int* in_sizes, int n_in,
                              void* d_out, int out_size, void* d_ws,
                              size_t ws_size, hipStream_t stream) {
  const float* x = (const float*)d_in[0];
  const int* ei = (const int*)d_in[1];
  const float* W1_0 = (const float*)d_in[2];
  const float* b1_0 = (const float*)d_in[3];
  const float* W2_0 = (const float*)d_in[4];
  const float* b2_0 = (const float*)d_in[5];
  const float* W1_1 = (const float*)d_in[6];
  const float* b1_1 = (const float*)d_in[7];
  const float* W2_1 = (const float*)d_in[8];
  const float* b2_1 = (const float*)d_in[9];
  const float* Wr = (const float*)d_in[10];
  const float* br = (const float*)d_in[11];

  const int M = in_sizes[0] / HIDDEN;  // 50000 nodes
  const int E = in_sizes[1] / 2;       // 800000 edges
  const int* src = ei;
  const int* dst = ei + E;
  const int NB = (M + NPB - 1) >> NB_SHIFT;  // 391 buckets

  // workspace layout. pairs (6.4 MB) overlays A: pairs die when build_csr
  // finishes; A is first written by aggregate, which launches after.
  float* A = (float*)d_ws;                   // [M,128] fp32 agg output
  int2* pairs = (int2*)d_ws;                 // [E] partitioned (src,dst)
  f16* xh = (f16*)(A + (size_t)M * HIDDEN);  // [M,128] fp16 features
  f16* Bh = xh + (size_t)M * HIDDEN;         // [M,128] fp16 layer-0 hidden
  int* rowptr = (int*)(Bh + (size_t)M * HIDDEN); // [M+1]
  int* col = rowptr + M + 1;                 // [E]
  int* bcnt = col + E;                       // [512]
  int* pairOff = bcnt + 512;                 // [513]
  int* gCursor = pairOff + 513;              // [512]
  ushort* Wpk = (ushort*)(gCursor + 512);    // 4 x (hi 32KB + lo 32KB)

  const int aggBlocks = (int)(((size_t)M * 64 + 255) / 256);
  const int mlpBlocks = (M + 63) / 64;
  const int cvtBlocks = (M * 16 + 255) / 256;  // M*128/8 threads
  const int edgeBlocks = (E + EPB - 1) / EPB;
  float* out = (float*)d_out;

  // ---- prepack weights + fp16 feature copy (independent of CSR chain)
  prepack_kernel<<<32, 256, 0, stream>>>(W1_0, W2_0, W1_1, W2_1, Wpk);
  f2h_kernel<<<cvtBlocks, 256, 0, stream>>>(x, xh, M * 16);

  // ---- build CSR via bucket sort (replaces hist/scan/fill random scatter)
  hipMemsetAsync(bcnt, 0, 512 * sizeof(int), stream);
  bucket_hist_kernel<<<edgeBlocks, 256, 0, stream>>>(dst, bcnt, E, NB);
  scan_buckets_kernel<<<1, 256, 0, stream>>>(bcnt, pairOff, gCursor, NB);
  partition_kernel<<<edgeBlocks, 256, 0, stream>>>(src, dst, gCursor, pairs,
                                                   E, NB);
  build_csr_kernel<<<NB, 256, 0, stream>>>(pairs, pairOff, rowptr, col, M, E,
                                           NB);

  // ---- layer 0: agg(fp16 x) -> fused MFMA MLP -> Bh (fp16)
  aggregate_kernel<<<aggBlocks, 256, 0, stream>>>(xh, rowptr, col, A, M);
  mlp_mfma_kernel<<<mlpBlocks, 256, 0, stream>>>(
      A, Wpk, b1_0, Wpk + 32768, b2_0, Bh, nullptr, nullptr, nullptr, M, 0);

  // ---- layer 1: agg(fp16 Bh) -> fused MFMA MLP + readout -> out
  aggregate_kernel<<<aggBlocks, 256, 0, stream>>>(Bh, rowptr, col, A, M);
  mlp_mfma_kernel<<<mlpBlocks, 256, 0, stream>>>(
      A, Wpk + 65536, b1_1, Wpk + 98304, b2_1, nullptr, Wr, br, out, M, 1);
}

// Round 5
// 254.140 us; speedup vs baseline: 1.9406x; 1.1199x over previous
//
#include <hip/hip_runtime.h>

#define HIDDEN 128
#define NB_SHIFT 7            // 128 dst nodes per bucket
#define NPB 128               // nodes per bucket
#define EPB 4096              // edges per partition/hist block

typedef __attribute__((ext_vector_type(8))) short short8;
typedef __attribute__((ext_vector_type(4))) float f32x4;
typedef _Float16 f16;
typedef __attribute__((ext_vector_type(8))) _Float16 f16x8;

// float -> bf16 (RNE), and back
__device__ __forceinline__ ushort f2bf(float a) {
  union { float f; unsigned u; } c; c.f = a;
  return (ushort)((c.u + 0x7FFFu + ((c.u >> 16) & 1u)) >> 16);
}
__device__ __forceinline__ float bf2f(ushort h) {
  union { unsigned u; float f; } c; c.u = ((unsigned)h) << 16;
  return c.f;
}

// ---------------------------------------------------------------------------
// CSR build A: per-bucket edge histogram (LDS-local, then merge).
// ---------------------------------------------------------------------------
__global__ __launch_bounds__(256) void bucket_hist_kernel(
    const int* __restrict__ dst, int* __restrict__ bcnt, int E, int NB) {
  __shared__ int loc[512];
  const int t = threadIdx.x;
  loc[t] = 0; loc[t + 256] = 0;
  __syncthreads();
  const int base = blockIdx.x * EPB;
  const int end = min(base + EPB, E);
  for (int e = base + t; e < end; e += 256)
    atomicAdd(&loc[dst[e] >> NB_SHIFT], 1);
  __syncthreads();
  for (int b = t; b < NB; b += 256)
    if (loc[b]) atomicAdd(&bcnt[b], loc[b]);
}

// ---------------------------------------------------------------------------
// CSR build B: exclusive scan of <=512 bucket counts -> pairOff + gCursor.
// ---------------------------------------------------------------------------
__global__ __launch_bounds__(256) void scan_buckets_kernel(
    const int* __restrict__ bcnt, int* __restrict__ pairOff,
    int* __restrict__ gCursor, int NB) {
  __shared__ int sh[512];
  const int t = threadIdx.x;
  const int v0 = (t < NB) ? bcnt[t] : 0;
  const int v1 = (t + 256 < NB) ? bcnt[t + 256] : 0;
  sh[t] = v0; sh[t + 256] = v1;
  __syncthreads();
#pragma unroll
  for (int off = 1; off < 512; off <<= 1) {
    int a = (t >= off) ? sh[t - off] : 0;
    int b = (t + 256 >= off) ? sh[t + 256 - off] : 0;
    __syncthreads();
    sh[t] += a; sh[t + 256] += b;
    __syncthreads();
  }
  const int e0 = sh[t] - v0;        // exclusive
  const int e1 = sh[t + 256] - v1;
  pairOff[t] = e0; gCursor[t] = e0;
  pairOff[t + 256] = e1; gCursor[t + 256] = e1;
  if (t == 255) pairOff[512] = sh[511];
}

// ---------------------------------------------------------------------------
// CSR build C: partition edges into bucket-contiguous PACKED pairs:
//   p = (dst & 127) << 25 | src      (needs src < 2^25; M = 50k << that)
// Halves the pair write traffic vs int2.
// ---------------------------------------------------------------------------
__global__ __launch_bounds__(256) void partition_kernel(
    const int* __restrict__ src, const int* __restrict__ dst,
    int* __restrict__ gCursor, int* __restrict__ pairs, int E, int NB) {
  __shared__ int loc[512];
  __shared__ int cur[512];
  const int t = threadIdx.x;
  loc[t] = 0; loc[t + 256] = 0;
  __syncthreads();
  const int base = blockIdx.x * EPB;
  const int end = min(base + EPB, E);
  for (int e = base + t; e < end; e += 256)
    atomicAdd(&loc[dst[e] >> NB_SHIFT], 1);
  __syncthreads();
  for (int b = t; b < NB; b += 256)
    cur[b] = loc[b] ? atomicAdd(&gCursor[b], loc[b]) : 0;
  __syncthreads();
  for (int e = base + t; e < end; e += 256) {
    const int d = dst[e];
    const int p = atomicAdd(&cur[d >> NB_SHIFT], 1);
    pairs[p] = ((d & (NPB - 1)) << 25) | src[e];
  }
}

// ---------------------------------------------------------------------------
// CSR build D: one block per bucket -> rowptr + col (dense, L2-resident).
// ---------------------------------------------------------------------------
__global__ __launch_bounds__(256) void build_csr_kernel(
    const int* __restrict__ pairs, const int* __restrict__ pairOff,
    int* __restrict__ rowptr, int* __restrict__ col, int M, int E, int NB) {
  __shared__ int deg[NPB];
  __shared__ int pre[NPB];
  __shared__ int cur[NPB];
  const int b = blockIdx.x;
  const int t = threadIdx.x;
  const int s = pairOff[b];
  const int e2 = pairOff[b + 1];
  const int nodeBase = b << NB_SHIFT;
  const int nNodes = min(NPB, M - nodeBase);
  if (t < NPB) deg[t] = 0;
  __syncthreads();
  for (int i = s + t; i < e2; i += 256)
    atomicAdd(&deg[((unsigned)pairs[i]) >> 25], 1);
  __syncthreads();
  if (t < NPB) pre[t] = deg[t];
  __syncthreads();
#pragma unroll
  for (int off = 1; off < NPB; off <<= 1) {
    int v = (t < NPB && t >= off) ? pre[t - off] : 0;
    __syncthreads();
    if (t < NPB) pre[t] += v;
    __syncthreads();
  }
  if (t < nNodes) rowptr[nodeBase + t] = s + pre[t] - deg[t];
  if (b == NB - 1 && t == 0) rowptr[M] = E;
  if (t < NPB) cur[t] = pre[t] - deg[t];
  __syncthreads();
  for (int i = s + t; i < e2; i += 256) {
    const int pr = pairs[i];
    const int pos = s + atomicAdd(&cur[((unsigned)pr) >> 25], 1);
    col[pos] = pr & 0x1FFFFFF;
  }
}

// ---------------------------------------------------------------------------
// fp32 -> fp16 feature convert (8 elems/thread)
// ---------------------------------------------------------------------------
__global__ __launch_bounds__(256) void f2h_kernel(const float* __restrict__ in,
                                                  f16* __restrict__ out, int n8) {
  int i = blockIdx.x * 256 + threadIdx.x;
  if (i >= n8) return;
  const float4* p = (const float4*)(in + (size_t)i * 8);
  float4 a = p[0], b = p[1];
  f16x8 o;
  o[0] = (f16)a.x; o[1] = (f16)a.y; o[2] = (f16)a.z; o[3] = (f16)a.w;
  o[4] = (f16)b.x; o[5] = (f16)b.y; o[6] = (f16)b.z; o[7] = (f16)b.w;
  *(f16x8*)(out + (size_t)i * 8) = o;
}

// ---------------------------------------------------------------------------
// Prepack weights into MFMA B-fragment-linear bf16 hi/lo planes.
//   frag (ks, nf), lane, j  ->  k = ks*32 + (lane>>4)*8 + j, n = nf*16 + (lane&15)
// ---------------------------------------------------------------------------
__global__ __launch_bounds__(256) void prepack_kernel(
    const float* __restrict__ Wa, const float* __restrict__ Wb,
    const float* __restrict__ Wc, const float* __restrict__ Wd,
    ushort* __restrict__ out) {
  int idx = blockIdx.x * 256 + threadIdx.x;  // 0..8191
  int w = idx >> 11;
  int rem = idx & 2047;
  int ks = rem >> 9;
  int nf = (rem >> 6) & 7;
  int lane = rem & 63;
  const float* W = (w == 0) ? Wa : (w == 1) ? Wb : (w == 2) ? Wc : Wd;
  const int kbase = ks * 32 + (lane >> 4) * 8;
  const int n = nf * 16 + (lane & 15);
  ushort* oh = out + (size_t)w * 32768 + (size_t)rem * 8;
  ushort* ol = oh + 16384;
#pragma unroll
  for (int j = 0; j < 8; ++j) {
    float v = W[(size_t)(kbase + j) * HIDDEN + n];
    ushort h = f2bf(v);
    oh[j] = h;
    ol[j] = f2bf(v - bf2f(h));
  }
}

// ---------------------------------------------------------------------------
// FUSED GIN layer: gather-aggregate + MLP1 + MLP2 (+ optional readout), one
// kernel. Block = 64 nodes, 4 waves x 16 nodes. Lane (r,g) owns node row r's
// dims {ks*32+g*8..+8} -- the SAME decomposition as the MFMA A-fragment, so
// the gather accumulators feed GEMM1 directly from registers and the fp32
// intermediate A never exists in global memory (saves 51.2 MB/layer).
// Edge loop is lane-divergent (wave time ~ max degree of its 16 rows).
// fp32 acc -> split bf16 hi/lo -> 3 MFMAs per tile (~fp32 accuracy).
// Zero __syncthreads (wave-private h1 tile). LDS 33.8 KB, <=128 VGPR
// (launch_bounds 256,4) -> 4 blocks/CU.
// ---------------------------------------------------------------------------
__global__ __launch_bounds__(256, 4) void gin_layer_kernel(
    const f16* __restrict__ xh, const int* __restrict__ rowptr,
    const int* __restrict__ col, const ushort* __restrict__ W1p,
    const float* __restrict__ b1, const ushort* __restrict__ W2p,
    const float* __restrict__ b2, f16* __restrict__ Ch,
    const float* __restrict__ Wr, const float* __restrict__ br,
    float* __restrict__ outv, int M, int doReadout) {
  __shared__ float h1[4][16][132];
  const int t = threadIdx.x;
  const int lane = t & 63;
  const int w = t >> 6;
  const int r = lane & 15;     // node row within wave / D col index
  const int g = lane >> 4;     // dim-quarter owner / D row group
  const int mBase = blockIdx.x * 64 + w * 16;
  int arow = mBase + r;
  if (arow > M - 1) arow = M - 1;  // clamp: garbage only affects rows >= M

  // ---- fused aggregation: a32[ks][j] = xh[arow] + sum_e xh[col[e]]
  float a32[4][8];
  {
    const f16* rp = xh + (size_t)arow * HIDDEN + g * 8;
    f16x8 s0 = *(const f16x8*)(rp);
    f16x8 s1 = *(const f16x8*)(rp + 32);
    f16x8 s2 = *(const f16x8*)(rp + 64);
    f16x8 s3 = *(const f16x8*)(rp + 96);
#pragma unroll
    for (int j = 0; j < 8; ++j) {
      a32[0][j] = (float)s0[j]; a32[1][j] = (float)s1[j];
      a32[2][j] = (float)s2[j]; a32[3][j] = (float)s3[j];
    }
    const int s = rowptr[arow];
    const int e = rowptr[arow + 1];
    int i = s;
    for (; i + 1 < e; i += 2) {
      const int c0 = col[i], c1 = col[i + 1];
      const f16* p0 = xh + (size_t)c0 * HIDDEN + g * 8;
      const f16* p1 = xh + (size_t)c1 * HIDDEN + g * 8;
      f16x8 u0 = *(const f16x8*)(p0);
      f16x8 u1 = *(const f16x8*)(p0 + 32);
      f16x8 u2 = *(const f16x8*)(p0 + 64);
      f16x8 u3 = *(const f16x8*)(p0 + 96);
      f16x8 v0 = *(const f16x8*)(p1);
      f16x8 v1 = *(const f16x8*)(p1 + 32);
      f16x8 v2 = *(const f16x8*)(p1 + 64);
      f16x8 v3 = *(const f16x8*)(p1 + 96);
#pragma unroll
      for (int j = 0; j < 8; ++j) {
        a32[0][j] += (float)u0[j] + (float)v0[j];
        a32[1][j] += (float)u1[j] + (float)v1[j];
        a32[2][j] += (float)u2[j] + (float)v2[j];
        a32[3][j] += (float)u3[j] + (float)v3[j];
      }
    }
    if (i < e) {
      const int c0 = col[i];
      const f16* p0 = xh + (size_t)c0 * HIDDEN + g * 8;
      f16x8 u0 = *(const f16x8*)(p0);
      f16x8 u1 = *(const f16x8*)(p0 + 32);
      f16x8 u2 = *(const f16x8*)(p0 + 64);
      f16x8 u3 = *(const f16x8*)(p0 + 96);
#pragma unroll
      for (int j = 0; j < 8; ++j) {
        a32[0][j] += (float)u0[j];
        a32[1][j] += (float)u1[j];
        a32[2][j] += (float)u2[j];
        a32[3][j] += (float)u3[j];
      }
    }
  }

  f32x4 acc[8];
#pragma unroll
  for (int i = 0; i < 8; ++i) acc[i] = (f32x4){0.f, 0.f, 0.f, 0.f};

  // ---- GEMM1: acc[nf] += a32(16x128) @ W1[:, nf*16..]
#pragma unroll
  for (int ks = 0; ks < 4; ++ks) {
    short8 ah, al;
#pragma unroll
    for (int j = 0; j < 8; ++j) {
      ushort h = f2bf(a32[ks][j]);
      ah[j] = (short)h;
      al[j] = (short)f2bf(a32[ks][j] - bf2f(h));
    }
#pragma unroll
    for (int nf = 0; nf < 8; ++nf) {
      const ushort* bp = W1p + ((size_t)(ks * 8 + nf) * 64 + lane) * 8;
      short8 bh = *(const short8*)bp;
      short8 bl = *(const short8*)(bp + 16384);
      acc[nf] = __builtin_amdgcn_mfma_f32_16x16x32_bf16(ah, bh, acc[nf], 0, 0, 0);
      acc[nf] = __builtin_amdgcn_mfma_f32_16x16x32_bf16(al, bh, acc[nf], 0, 0, 0);
      acc[nf] = __builtin_amdgcn_mfma_f32_16x16x32_bf16(ah, bl, acc[nf], 0, 0, 0);
    }
  }

  // ---- bias + relu, park h1 in wave-private LDS (row=4g+q, col=nf*16+r)
#pragma unroll
  for (int nf = 0; nf < 8; ++nf) {
    float bv = b1[nf * 16 + r];
#pragma unroll
    for (int q = 0; q < 4; ++q)
      h1[w][g * 4 + q][nf * 16 + r] = fmaxf(acc[nf][q] + bv, 0.f);
    acc[nf] = (f32x4){0.f, 0.f, 0.f, 0.f};
  }

  // ---- GEMM2: acc[nf] += h1(16x128) @ W2[:, nf*16..] (A-frags from LDS)
#pragma unroll
  for (int ks = 0; ks < 4; ++ks) {
    const float* hp = &h1[w][r][ks * 32 + g * 8];
    float4 a0 = *(const float4*)hp;
    float4 a1 = *(const float4*)(hp + 4);
    float av[8] = {a0.x, a0.y, a0.z, a0.w, a1.x, a1.y, a1.z, a1.w};
    short8 ah, al;
#pragma unroll
    for (int j = 0; j < 8; ++j) {
      ushort h = f2bf(av[j]);
      ah[j] = (short)h;
      al[j] = (short)f2bf(av[j] - bf2f(h));
    }
#pragma unroll
    for (int nf = 0; nf < 8; ++nf) {
      const ushort* bp = W2p + ((size_t)(ks * 8 + nf) * 64 + lane) * 8;
      short8 bh = *(const short8*)bp;
      short8 bl = *(const short8*)(bp + 16384);
      acc[nf] = __builtin_amdgcn_mfma_f32_16x16x32_bf16(ah, bh, acc[nf], 0, 0, 0);
      acc[nf] = __builtin_amdgcn_mfma_f32_16x16x32_bf16(al, bh, acc[nf], 0, 0, 0);
      acc[nf] = __builtin_amdgcn_mfma_f32_16x16x32_bf16(ah, bl, acc[nf], 0, 0, 0);
    }
  }

  if (!doReadout) {
    // bias + relu -> LDS, then coalesced fp16 stores
#pragma unroll
    for (int nf = 0; nf < 8; ++nf) {
      float bv = b2[nf * 16 + r];
#pragma unroll
      for (int q = 0; q < 4; ++q)
        h1[w][g * 4 + q][nf * 16 + r] = fmaxf(acc[nf][q] + bv, 0.f);
    }
    const int rr = lane >> 2;          // 0..15
    const int c0 = (lane & 3) * 32;    // 0,32,64,96
    const int gm = blockIdx.x * 64 + w * 16 + rr;
    if (gm < M) {
#pragma unroll
      for (int i = 0; i < 4; ++i) {
        float4 v0 = *(const float4*)&h1[w][rr][c0 + i * 8];
        float4 v1 = *(const float4*)&h1[w][rr][c0 + i * 8 + 4];
        f16x8 o;
        o[0] = (f16)v0.x; o[1] = (f16)v0.y; o[2] = (f16)v0.z; o[3] = (f16)v0.w;
        o[4] = (f16)v1.x; o[5] = (f16)v1.y; o[6] = (f16)v1.z; o[7] = (f16)v1.w;
        *(f16x8*)(Ch + (size_t)gm * HIDDEN + c0 + i * 8) = o;
      }
    }
  } else {
    // readout: out[m] = relu(h2)[m,:] . Wr + br, reduced across 16 r-lanes
    float p[4] = {0.f, 0.f, 0.f, 0.f};
#pragma unroll
    for (int nf = 0; nf < 8; ++nf) {
      float bv = b2[nf * 16 + r];
      float wv = Wr[nf * 16 + r];
#pragma unroll
      for (int q = 0; q < 4; ++q) {
        float h = fmaxf(acc[nf][q] + bv, 0.f);
        p[q] += h * wv;
      }
    }
#pragma unroll
    for (int q = 0; q < 4; ++q) {
      p[q] += __shfl_xor(p[q], 8);
      p[q] += __shfl_xor(p[q], 4);
      p[q] += __shfl_xor(p[q], 2);
      p[q] += __shfl_xor(p[q], 1);
    }
    if (r == 0) {
      float brv = br[0];
#pragma unroll
      for (int q = 0; q < 4; ++q) {
        int gm = mBase + g * 4 + q;
        if (gm < M) outv[gm] = p[q] + brv;
      }
    }
  }
}

extern "C" void kernel_launch(void* const* d_in, const int* in_sizes, int n_in,
                              void* d_out, int out_size, void* d_ws,
                              size_t ws_size, hipStream_t stream) {
  const float* x = (const float*)d_in[0];
  const int* ei = (const int*)d_in[1];
  const float* W1_0 = (const float*)d_in[2];
  const float* b1_0 = (const float*)d_in[3];
  const float* W2_0 = (const float*)d_in[4];
  const float* b2_0 = (const float*)d_in[5];
  const float* W1_1 = (const float*)d_in[6];
  const float* b1_1 = (const float*)d_in[7];
  const float* W2_1 = (const float*)d_in[8];
  const float* b2_1 = (const float*)d_in[9];
  const float* Wr = (const float*)d_in[10];
  const float* br = (const float*)d_in[11];

  const int M = in_sizes[0] / HIDDEN;  // 50000 nodes
  const int E = in_sizes[1] / 2;       // 800000 edges
  const int* src = ei;
  const int* dst = ei + E;
  const int NB = (M + NPB - 1) >> NB_SHIFT;  // 391 buckets

  // workspace layout. pairs dies after build_csr; scratch region reused.
  int* pairs = (int*)d_ws;                   // [E] packed (dst&127)<<25|src
  f16* xh = (f16*)(pairs + E);               // [M,128] fp16 features
  f16* Bh = xh + (size_t)M * HIDDEN;         // [M,128] fp16 layer-0 hidden
  int* rowptr = (int*)(Bh + (size_t)M * HIDDEN); // [M+1]
  int* col = rowptr + M + 1;                 // [E]
  int* bcnt = col + E;                       // [512]
  int* pairOff = bcnt + 512;                 // [513]
  int* gCursor = pairOff + 513;              // [512]
  ushort* Wpk = (ushort*)(gCursor + 512);    // 4 x (hi 32KB + lo 32KB)

  const int mlpBlocks = (M + 63) / 64;
  const int cvtBlocks = (M * 16 + 255) / 256;  // M*128/8 threads
  const int edgeBlocks = (E + EPB - 1) / EPB;
  float* out = (float*)d_out;

  // ---- prepack weights + fp16 feature copy (independent of CSR chain)
  prepack_kernel<<<32, 256, 0, stream>>>(W1_0, W2_0, W1_1, W2_1, Wpk);
  f2h_kernel<<<cvtBlocks, 256, 0, stream>>>(x, xh, M * 16);

  // ---- build CSR via bucket sort
  hipMemsetAsync(bcnt, 0, 512 * sizeof(int), stream);
  bucket_hist_kernel<<<edgeBlocks, 256, 0, stream>>>(dst, bcnt, E, NB);
  scan_buckets_kernel<<<1, 256, 0, stream>>>(bcnt, pairOff, gCursor, NB);
  partition_kernel<<<edgeBlocks, 256, 0, stream>>>(src, dst, gCursor, pairs,
                                                   E, NB);
  build_csr_kernel<<<NB, 256, 0, stream>>>(pairs, pairOff, rowptr, col, M, E,
                                           NB);

  // ---- layer 0: fused gather+MLP (xh -> Bh fp16)
  gin_layer_kernel<<<mlpBlocks, 256, 0, stream>>>(
      xh, rowptr, col, Wpk, b1_0, Wpk + 32768, b2_0, Bh,
      nullptr, nullptr, nullptr, M, 0);

  // ---- layer 1: fused gather+MLP+readout (Bh -> out)
  gin_layer_kernel<<<mlpBlocks, 256, 0, stream>>>(
      Bh, rowptr, col, Wpk + 65536, b1_1, Wpk + 98304, b2_1, nullptr,
      Wr, br, out, M, 1);
}